// Round 1
// baseline (1369.162 us; speedup 1.0000x reference)
//
#include <hip/hip_runtime.h>

// Problem constants: B=2048, M=64, HID=1024, H=8, D=128
#define Bsz 2048
#define Mlen 64
#define HID 1024
#define NH 8
#define DH 128

// ---------------------------------------------------------------------------
// Kernel 1: fold Wqb[h*128+d, i] = sum_e Wb[d,e] * Wq[h*128+e, i]
// grid (4, 128): blockIdx.x = column block (256 cols), blockIdx.y = h*16 + d-group
__global__ __launch_bounds__(256) void fold_wqb(
    const float* __restrict__ Wb, const float* __restrict__ Wq,
    float* __restrict__ Wqb)
{
    int h  = blockIdx.y >> 4;
    int d0 = (blockIdx.y & 15) * 8;
    int i  = blockIdx.x * 256 + threadIdx.x;
    __shared__ float wb[8][128];
    for (int j = threadIdx.x; j < 8 * 128; j += 256)
        wb[j >> 7][j & 127] = Wb[(d0 + (j >> 7)) * 128 + (j & 127)];
    __syncthreads();
    float acc[8] = {};
    #pragma unroll 8
    for (int e = 0; e < 128; ++e) {
        float wq = Wq[(size_t)((h << 7) + e) * HID + i];
        #pragma unroll
        for (int dd = 0; dd < 8; ++dd) acc[dd] += wb[dd][e] * wq;
    }
    #pragma unroll
    for (int dd = 0; dd < 8; ++dd)
        Wqb[(size_t)((h << 7) + d0 + dd) * HID + i] = acc[dd];
}

// ---------------------------------------------------------------------------
// Generic fp32 tiled GEMM:  C[row, col] = sum_k A[row, k] * W[col, k]  (+bias)
// A: M x K row-major (row stride lda), W: N x K row-major (row stride ldw)
// per-z offsets select head sub-blocks. BM=BN=64, BK=16, 256 threads, 4x4/thread.
__global__ __launch_bounds__(256) void gemm_awt(
    const float* __restrict__ A, int lda, int aOffZ,
    const float* __restrict__ W, int ldw, int wOffZ,
    float* __restrict__ C, int ldc, int cOffZ,
    int K, const float* __restrict__ bias)
{
    __shared__ float As[16][64];
    __shared__ float Ws[16][64];
    const float* Ab = A + (size_t)blockIdx.z * aOffZ;
    const float* Wb = W + (size_t)blockIdx.z * wOffZ;
    float*       Cb = C + (size_t)blockIdx.z * cOffZ;
    int row0 = blockIdx.y * 64, col0 = blockIdx.x * 64;
    int t = threadIdx.x;
    int tx = t & 15, ty = t >> 4;
    int lr = t >> 2, lk = (t & 3) * 4;
    float acc[4][4] = {};
    for (int k0 = 0; k0 < K; k0 += 16) {
        float4 av = *(const float4*)(Ab + (size_t)(row0 + lr) * lda + k0 + lk);
        float4 wv = *(const float4*)(Wb + (size_t)(col0 + lr) * ldw + k0 + lk);
        __syncthreads();
        As[lk + 0][lr] = av.x; As[lk + 1][lr] = av.y;
        As[lk + 2][lr] = av.z; As[lk + 3][lr] = av.w;
        Ws[lk + 0][lr] = wv.x; Ws[lk + 1][lr] = wv.y;
        Ws[lk + 2][lr] = wv.z; Ws[lk + 3][lr] = wv.w;
        __syncthreads();
        #pragma unroll
        for (int kk = 0; kk < 16; ++kk) {
            float4 a4 = *(const float4*)&As[kk][ty * 4];
            float4 w4 = *(const float4*)&Ws[kk][tx * 4];
            float a[4] = {a4.x, a4.y, a4.z, a4.w};
            float w[4] = {w4.x, w4.y, w4.z, w4.w};
            #pragma unroll
            for (int i = 0; i < 4; ++i)
                #pragma unroll
                for (int j = 0; j < 4; ++j)
                    acc[i][j] += a[i] * w[j];
        }
    }
    #pragma unroll
    for (int i = 0; i < 4; ++i) {
        int row = row0 + ty * 4 + i;
        #pragma unroll
        for (int j = 0; j < 4; ++j) {
            int col = col0 + tx * 4 + j;
            float cv = acc[i][j];
            if (bias) cv += bias[(size_t)blockIdx.z * cOffZ + col];
            Cb[(size_t)row * ldc + col] = cv;
        }
    }
}

// ---------------------------------------------------------------------------
// Generic fp32 tiled GEMM:  C = A @ B, B is K x N row-major.
__global__ __launch_bounds__(256) void gemm_ab(
    const float* __restrict__ A, int lda, int aOffZ,
    const float* __restrict__ B, int ldb, int bOffZ,
    float* __restrict__ C, int ldc, int cOffZ, int K)
{
    __shared__ float As[16][64];
    __shared__ float Bs[16][64];
    const float* Ab = A + (size_t)blockIdx.z * aOffZ;
    const float* Bb = B + (size_t)blockIdx.z * bOffZ;
    float*       Cb = C + (size_t)blockIdx.z * cOffZ;
    int row0 = blockIdx.y * 64, col0 = blockIdx.x * 64;
    int t = threadIdx.x;
    int tx = t & 15, ty = t >> 4;
    int lr = t >> 2, lk = (t & 3) * 4;   // A loader
    int bk = t >> 4, bn = (t & 15) * 4;  // B loader
    float acc[4][4] = {};
    for (int k0 = 0; k0 < K; k0 += 16) {
        float4 av = *(const float4*)(Ab + (size_t)(row0 + lr) * lda + k0 + lk);
        float4 bv = *(const float4*)(Bb + (size_t)(k0 + bk) * ldb + col0 + bn);
        __syncthreads();
        As[lk + 0][lr] = av.x; As[lk + 1][lr] = av.y;
        As[lk + 2][lr] = av.z; As[lk + 3][lr] = av.w;
        *(float4*)&Bs[bk][bn] = bv;
        __syncthreads();
        #pragma unroll
        for (int kk = 0; kk < 16; ++kk) {
            float4 a4 = *(const float4*)&As[kk][ty * 4];
            float4 w4 = *(const float4*)&Bs[kk][tx * 4];
            float a[4] = {a4.x, a4.y, a4.z, a4.w};
            float w[4] = {w4.x, w4.y, w4.z, w4.w};
            #pragma unroll
            for (int i = 0; i < 4; ++i)
                #pragma unroll
                for (int j = 0; j < 4; ++j)
                    acc[i][j] += a[i] * w[j];
        }
    }
    #pragma unroll
    for (int i = 0; i < 4; ++i) {
        int row = row0 + ty * 4 + i;
        #pragma unroll
        for (int j = 0; j < 4; ++j)
            Cb[(size_t)row * ldc + col0 + tx * 4 + j] = acc[i][j];
    }
}

// ---------------------------------------------------------------------------
// Attention core (memory-bound): per batch b,
//   scores[h,m] = dot(QK[b,h,:], k[b,m,:]);  softmax over m;
//   VA[b,h,i]   = sum_m attn[h,m] * v[b,m,i]
__global__ __launch_bounds__(256) void attn_kernel(
    const float* __restrict__ k, const float* __restrict__ v,
    const float* __restrict__ QK, float* __restrict__ VA)
{
    __shared__ float qs[NH][HID];   // 32 KB
    __shared__ float sc[NH][Mlen];  // 2 KB
    __shared__ float at[NH][Mlen];  // 2 KB
    int b = blockIdx.x;
    int t = threadIdx.x;
    int l = t & 63, w = t >> 6;

    // stage QK[b] into LDS
    const float* qkb = QK + (size_t)b * (NH * HID);
    #pragma unroll
    for (int j = 0; j < NH; ++j)
        *(float4*)&qs[j][t * 4] = *(const float4*)(qkb + j * HID + t * 4);
    __syncthreads();

    // scores: wave w handles m in [w*16, w*16+16), 2 rows at a time
    const float* kb = k + (size_t)b * Mlen * HID;
    for (int mi = 0; mi < 16; mi += 2) {
        int m0 = w * 16 + mi;
        float4 kv[2][4];
        #pragma unroll
        for (int u = 0; u < 2; ++u)
            #pragma unroll
            for (int j = 0; j < 4; ++j)
                kv[u][j] = *(const float4*)(kb + (size_t)(m0 + u) * HID + j * 256 + l * 4);
        float acc[2][NH] = {};
        #pragma unroll
        for (int u = 0; u < 2; ++u)
            #pragma unroll
            for (int j = 0; j < 4; ++j) {
                int i0 = j * 256 + l * 4;
                #pragma unroll
                for (int h = 0; h < NH; ++h) {
                    float4 q4 = *(const float4*)&qs[h][i0];
                    acc[u][h] += kv[u][j].x * q4.x + kv[u][j].y * q4.y
                               + kv[u][j].z * q4.z + kv[u][j].w * q4.w;
                }
            }
        #pragma unroll
        for (int u = 0; u < 2; ++u)
            #pragma unroll
            for (int h = 0; h < NH; ++h) {
                float s = acc[u][h];
                #pragma unroll
                for (int off = 32; off > 0; off >>= 1)
                    s += __shfl_xor(s, off, 64);
                if (l == 0) sc[h][m0 + u] = s;
            }
    }
    __syncthreads();

    // softmax over m (wave w handles heads w and w+4); m = lane
    for (int h = w; h < NH; h += 4) {
        float s = sc[h][l];
        float mx = s;
        #pragma unroll
        for (int off = 32; off > 0; off >>= 1)
            mx = fmaxf(mx, __shfl_xor(mx, off, 64));
        float e = __expf(s - mx);
        float sum = e;
        #pragma unroll
        for (int off = 32; off > 0; off >>= 1)
            sum += __shfl_xor(sum, off, 64);
        at[h][l] = e / sum;
    }
    __syncthreads();

    // VA: thread t owns columns [t*4, t*4+4)
    const float* vb = v + (size_t)b * Mlen * HID;
    int i0 = t * 4;
    float acc[NH][4] = {};
    for (int m0 = 0; m0 < Mlen; m0 += 8) {
        float4 vv[8];
        #pragma unroll
        for (int u = 0; u < 8; ++u)
            vv[u] = *(const float4*)(vb + (size_t)(m0 + u) * HID + i0);
        #pragma unroll
        for (int u = 0; u < 8; ++u)
            #pragma unroll
            for (int h = 0; h < NH; ++h) {
                float a = at[h][m0 + u];
                acc[h][0] += a * vv[u].x; acc[h][1] += a * vv[u].y;
                acc[h][2] += a * vv[u].z; acc[h][3] += a * vv[u].w;
            }
    }
    float* vab = VA + (size_t)b * (NH * HID);
    #pragma unroll
    for (int h = 0; h < NH; ++h)
        *(float4*)(vab + h * HID + i0) =
            make_float4(acc[h][0], acc[h][1], acc[h][2], acc[h][3]);
}

// ---------------------------------------------------------------------------
extern "C" void kernel_launch(void* const* d_in, const int* in_sizes, int n_in,
                              void* d_out, int out_size, void* d_ws, size_t ws_size,
                              hipStream_t stream)
{
    (void)in_sizes; (void)n_in; (void)out_size; (void)ws_size;
    const float* q  = (const float*)d_in[0];
    const float* k  = (const float*)d_in[1];
    const float* v  = (const float*)d_in[2];
    const float* Wq = (const float*)d_in[3];
    const float* Wk = (const float*)d_in[4];
    const float* Wv = (const float*)d_in[5];
    const float* Wb = (const float*)d_in[6];
    const float* Wo = (const float*)d_in[7];
    const float* bo = (const float*)d_in[8];
    float* out = (float*)d_out;

    char* ws = (char*)d_ws;
    float* QK  = (float*)(ws);                           // 2048*8192*4 = 64 MB
    float* VA  = (float*)(ws + (size_t)67108864);        // 64 MB
    float* QB  = (float*)(ws + (size_t)134217728);       // 8 MB (reused as X)
    float* Wqb = (float*)(ws + (size_t)142606336);       // 4 MB
    float* X   = QB;  // QB dead after stage 3

    // 1. Wqb = fold(Wb, Wq)
    fold_wqb<<<dim3(4, 128), 256, 0, stream>>>(Wb, Wq, Wqb);
    // 2. QB = q @ Wqb^T           (2048 x 1024, K=1024)
    gemm_awt<<<dim3(16, 32, 1), 256, 0, stream>>>(
        q, HID, 0, Wqb, HID, 0, QB, HID, 0, HID, nullptr);
    // 3. QK_h = QB_h @ Wk_h       (per head: 2048 x 1024, K=128)
    gemm_ab<<<dim3(16, 32, 8), 256, 0, stream>>>(
        QB, HID, DH, Wk, HID, DH * HID, QK, NH * HID, HID, DH);
    // 4. attention core: scores -> softmax -> VA
    attn_kernel<<<dim3(Bsz), 256, 0, stream>>>(k, v, QK, VA);
    // 5. X_h = VA_h @ Wv_h^T      (per head: 2048 x 128, K=1024)
    gemm_awt<<<dim3(2, 32, 8), 256, 0, stream>>>(
        VA, NH * HID, HID, Wv, HID, DH * HID, X, HID, DH, HID, nullptr);
    // 6. out = X @ Wo^T + bo      (2048 x 1024, K=1024)
    gemm_awt<<<dim3(16, 32, 1), 256, 0, stream>>>(
        X, HID, 0, Wo, HID, 0, out, HID, 0, HID, bo);
}